// Round 12
// baseline (292.205 us; speedup 1.0000x reference)
//
#include <hip/hip_runtime.h>

typedef _Float16 half8 __attribute__((ext_vector_type(8)));
typedef float f32x16 __attribute__((ext_vector_type(16)));
typedef float f32x4 __attribute__((ext_vector_type(4)));

#define N_IMG 32
#define C_IN  128
#define H_IN  56
#define W_IN  56
#define F_OUT 256
#define HO    54
#define WO    54
#define KKDIM 1152
#define NKB   18            // 1152 / 64

#define T2_BYTES (N_IMG * W_IN * H_IN * C_IN * 2)   // 25,690,112
#define BP_OFF   T2_BYTES
#define BP_BYTES (NKB * F_OUT * 64 * 2)             // 589,824
#define WS_NEED  (BP_OFF + BP_BYTES)

#define SLAB_I_STRIDE 14336        // 56 rows * 256 B
#define A_REGION  88576            // padded (h>=54 garbage rows, discarded)
#define B_CHUNK   32768
#define SMEM_BYTES A_REGION        // A only — B no longer staged in LDS

#define ASM_BAR() asm volatile("s_barrier" ::: "memory")

static __device__ inline unsigned pack2(float a, float b) {
    union { _Float16 h[2]; unsigned u; } x;
    x.h[0] = (_Float16)a; x.h[1] = (_Float16)b; return x.u;
}

// ---------------------------------------------------------------------------
// Kernel 1 v2 (verified R10/R11): NCHW fp32 -> T2[n][ww][hh][c] fp16, slot j
// of a 256B c-row holds c-group j^(hh&15).
// ---------------------------------------------------------------------------
__global__ __launch_bounds__(256) void k_transpose(const float* __restrict__ in,
                                                   _Float16* __restrict__ t2) {
    __shared__ char Lt[4 * 56 * 256];   // 57,344 B
    const int n   = blockIdx.y;
    const int hh0 = blockIdx.x * 4;
    const int t   = threadIdx.x;
    const int lane = t & 63, wid = t >> 6;
    const float4* in4 = (const float4*)in;

    if (lane < 56) {
        const int ww4 = lane % 14, hhi = lane / 14;
        const int X    = lane & 15;
        const int rowb = (hhi * 56 + ww4 * 4) * 256;
        const int gbase = ((n * 128) * 56 + hh0 + hhi) * 14 + ww4;
#pragma unroll 4
        for (int p = 0; p < 16; ++p) {
            const int c0 = wid * 32 + p * 2;
            float4 a = in4[gbase + c0 * 56 * 14];
            float4 b = in4[gbase + (c0 + 1) * 56 * 14];
            const int cb = c0 * 2;
            const int swz = (cb & 15) | ((((cb >> 4)) ^ X) << 4);
            const float* af = (const float*)&a;
            const float* bf = (const float*)&b;
#pragma unroll
            for (int i = 0; i < 4; ++i)
                *(unsigned*)(Lt + rowb + i * 256 + swz) = pack2(af[i], bf[i]);
        }
    }
    __syncthreads();

    {
        const int j = t & 15;
        int ww = t >> 4, hhi = 0;
        for (int it = 0; it < 14; ++it) {
            const int X  = (hhi * 14 + (ww >> 2)) & 15;
            const int hh = hh0 + hhi;
            const int s  = j ^ (hh & 15) ^ X;
            int4 v = *(const int4*)(Lt + (hhi * 56 + ww) * 256 + s * 16);
            char* dst = (char*)t2 + ((size_t)((n * 56 + ww) * 56 + hh)) * 256 + j * 16;
            *(int4*)dst = v;
            ww += 16; if (ww >= 56) { ww -= 56; ++hhi; }
        }
    }
}

// ---------------------------------------------------------------------------
// Kernel 2 v3: weights fp32 [F][1152] -> Bp[kb][f][kin] fp16, LINEAR layout
// (swizzle removed — B is now read from global/L1 in k_gemm, not via LDS).
// ---------------------------------------------------------------------------
__global__ __launch_bounds__(256) void k_weights(const float* __restrict__ kern,
                                                 _Float16* __restrict__ bp) {
    const int tid = blockIdx.x * 256 + threadIdx.x;
    if (tid >= F_OUT * KKDIM / 4) return;
    const float4 v = ((const float4*)kern)[tid];
    const int kq = tid % 288, f = tid / 288;
    const int kb   = kq >> 4;
    const int kin2 = (kq & 15) * 8;
    uint2 w; w.x = pack2(v.x, v.y); w.y = pack2(v.z, v.w);
    char* dst = (char*)bp + kb * B_CHUNK + f * 128 + kin2;
    *(uint2*)dst = w;
}

// ---------------------------------------------------------------------------
// Kernel 3 v6: implicit-GEMM MFMA, 8 waves (512 thr), wave = 64h x 128f.
// STRUCTURAL change vs v1-v5 (which all sat at 94-107us / 26-29% MfmaUtil):
//   B is NOT staged in LDS. Each wave loads its 16 B-fragments per K-chunk
//   directly from global (Bp is 576KB -> L2-resident; the 4x wm-duplication
//   hits L1). A stays LDS-resident (read-only after prologue).
//   => ZERO in-loop barriers / waitcnt. Waves free-run across all 18 chunks;
//   LDS burst<->MFMA serialization (the measured ~60% bubble) disappears;
//   matrix pipe (2048 cyc/chunk/block) becomes the limiting resource.
// ---------------------------------------------------------------------------
typedef const __attribute__((address_space(1))) unsigned int guint;
typedef __attribute__((address_space(3))) unsigned int luint;

__global__ __launch_bounds__(512, 2) void k_gemm(const _Float16* __restrict__ t2,
                                                 const _Float16* __restrict__ bp,
                                                 float* __restrict__ out) {
    extern __shared__ char smem[];
    char* As = smem;

    const int tid  = threadIdx.x;
    const int lane = tid & 63;
    const int wid  = tid >> 6;       // 0..7
    const int wm   = wid >> 1;       // w-col 0..3
    const int wf   = wid & 1;        // f half (128 cols)
    const int ln31 = lane & 31;
    const int kin2 = (lane >> 5) * 16;
    const int n  = blockIdx.y;
    const int w0 = blockIdx.x * 4;

    // ---- prologue: stage A slab only ----
    int navail = 56 - w0; if (navail > 6) navail = 6;
    const int bytesA = navail * SLAB_I_STRIDE;
    const char* t2n = (const char*)t2 + (size_t)(n * 56 + w0) * 56 * 256;
    for (int o = tid * 16; o < bytesA; o += 8192)   // wave-uniform trips
        __builtin_amdgcn_global_load_lds((guint*)(t2n + o), (luint*)(As + o), 16, 0, 0);

    f32x16 acc[2][4];
#pragma unroll
    for (int m2 = 0; m2 < 2; ++m2)
#pragma unroll
        for (int ft = 0; ft < 4; ++ft)
#pragma unroll
            for (int e = 0; e < 16; ++e)
                acc[m2][ft][e] = 0.0f;

    asm volatile("s_waitcnt vmcnt(0)" ::: "memory");
    ASM_BAR();   // the ONLY barrier: A slab resident; waves free-run after

    // lane-fixed part of the B address (linear Bp layout)
    const char* bpc = (const char*)bp;
    const char* bl  = bpc + (wf * 128 + ln31) * 128 + kin2;

    for (int kb = 0; kb < NKB; ++kb) {
        const int ij  = kb >> 1;
        const int iq  = ij / 3;            // w-offset
        const int jq  = ij - iq * 3;       // h-offset
        const int ch2 = (kb & 1) * 128;    // c byte offset of this 64-k chunk
        const int hh0 = ln31 + jq;
        const int Xa  = (hh0 & 15) << 4;
        const int abase = (wm + iq) * SLAB_I_STRIDE + hh0 * 256;
        const char* bk = bl + kb * B_CHUNK;

        // issue ALL 16 B-fragment loads for this chunk (VMEM, L1/L2-served);
        // compiler-tracked vmcnt lets s=0's MFMAs start as soon as its 4 land
        half8 bF[4][4];
#pragma unroll
        for (int s = 0; s < 4; ++s)
#pragma unroll
            for (int ft = 0; ft < 4; ++ft)
                bF[s][ft] = *(const half8*)(bk + ft * 4096 + s * 32);

#pragma unroll
        for (int s = 0; s < 4; ++s) {
            const int cb = ch2 + s * 32 + kin2;
            half8 aF0 = *(const half8*)(As + abase + (cb ^ Xa));
            half8 aF1 = *(const half8*)(As + abase + 8192 + (cb ^ Xa));
            __builtin_amdgcn_s_setprio(1);
#pragma unroll
            for (int ft = 0; ft < 4; ++ft) {
                acc[0][ft] = __builtin_amdgcn_mfma_f32_32x32x16_f16(aF0, bF[s][ft], acc[0][ft], 0, 0, 0);
                acc[1][ft] = __builtin_amdgcn_mfma_f32_32x32x16_f16(aF1, bF[s][ft], acc[1][ft], 0, 0, 0);
            }
            __builtin_amdgcn_s_setprio(0);
        }
    }

    // ---- epilogue (v1 layout, verified): C/D col=lane&31(f),
    //      row=(reg&3)+8*(reg>>2)+4*(lane>>5) over h
    const int w = w0 + wm;
    if (w < WO) {
        const int hi4 = (lane >> 5) * 4;
#pragma unroll
        for (int m2 = 0; m2 < 2; ++m2) {
#pragma unroll
            for (int ft = 0; ft < 4; ++ft) {
                const int f = wf * 128 + ft * 32 + ln31;
                float* op = out + ((size_t)(n * 256 + f) * 54 + w) * 54;
#pragma unroll
                for (int q = 0; q < 4; ++q) {
                    const int hb = m2 * 32 + q * 8 + hi4;
                    if (hb + 3 < HO) {
                        f32x4 v = { acc[m2][ft][4 * q + 0], acc[m2][ft][4 * q + 1],
                                    acc[m2][ft][4 * q + 2], acc[m2][ft][4 * q + 3] };
                        *(f32x4*)(op + hb) = v;
                    } else if (hb < HO) {   // hb == 52
                        op[hb]     = acc[m2][ft][4 * q + 0];
                        op[hb + 1] = acc[m2][ft][4 * q + 1];
                    }
                }
            }
        }
    }
}

// ---------------------------------------------------------------------------
// Fallback (only if ws too small)
// ---------------------------------------------------------------------------
__global__ __launch_bounds__(256) void k_naive(const float* __restrict__ in,
                                               const float* __restrict__ kern,
                                               float* __restrict__ out) {
    const int idx = blockIdx.x * 256 + threadIdx.x;
    const int total = N_IMG * F_OUT * WO * HO;
    if (idx >= total) return;
    const int h = idx % 54;
    const int w = (idx / 54) % 54;
    const int f = (idx / (54 * 54)) % 256;
    const int n = idx / (54 * 54 * 256);
    float s = 0.f;
    for (int ij = 0; ij < 9; ++ij) {
        const int i = ij / 3, j = ij % 3;
        const float* ip = in + ((size_t)(n * 128) * 56 + (h + j)) * 56 + (w + i);
        const float* kp = kern + (size_t)f * KKDIM + ij * 128;
        for (int c = 0; c < 128; ++c) s += ip[(size_t)c * 3136] * kp[c];
    }
    out[idx] = s;
}

extern "C" void kernel_launch(void* const* d_in, const int* in_sizes, int n_in,
                              void* d_out, int out_size, void* d_ws, size_t ws_size,
                              hipStream_t stream) {
    const float* in   = (const float*)d_in[0];
    const float* kern = (const float*)d_in[1];
    float* out = (float*)d_out;

    if (ws_size < (size_t)WS_NEED) {
        const int total = N_IMG * F_OUT * WO * HO;
        k_naive<<<(total + 255) / 256, 256, 0, stream>>>(in, kern, out);
        return;
    }

    _Float16* t2 = (_Float16*)d_ws;
    _Float16* bp = (_Float16*)((char*)d_ws + BP_OFF);

    k_transpose<<<dim3(14, 32), 256, 0, stream>>>(in, t2);
    k_weights<<<288, 256, 0, stream>>>(kern, bp);

    (void)hipFuncSetAttribute((const void*)k_gemm,
                              hipFuncAttributeMaxDynamicSharedMemorySize, SMEM_BYTES);
    k_gemm<<<dim3(14, 32), 512, SMEM_BYTES, stream>>>(t2, bp, out);
}